// Round 12
// baseline (161.136 us; speedup 1.0000x reference)
//
#include <hip/hip_runtime.h>

#define BB 4
#define AA 512
#define AH 256   // angles per grid-z half
#define DD 729
#define HH 512
#define WW 512
#define TSZ 16   // pixel tile 16x16
#define CH  32   // angles staged per chunk
#define WIN 32   // window bins per angle

typedef float    f4v __attribute__((ext_vector_type(4)));
typedef _Float16 h4v __attribute__((ext_vector_type(4)));

__device__ inline float buf_load1(__amdgpu_buffer_rsrc_t r, int vo) {
    union { unsigned int u; float f; } c;
    c.u = __builtin_amdgcn_raw_buffer_load_b32(r, vo, 0, 0);
    return c.f;
}

// R11: 86.5us == the fp32-window LDS floor (2x ds_read_b128 = 32B/thread/angle
// -> 82us at 85 B/cyc). R12: fp16 window [angle][bin][b4] = 8B/bin -> taps are
// 2x ds_read_b64 (16B/angle, halves LDS bytes); lerp still fp32 after unpack.
// CH=32 halves barrier count. Staging e-fastest: 128B-coalesced global reads,
// halfword LDS writes at 8B stride = 2-way bank aliasing = free (m136).
__global__ __launch_bounds__(256, 8) void bp_kernel(
    const float* __restrict__ sino,
    const float* __restrict__ vol_origin,
    const float* __restrict__ det_origin,
    const float* __restrict__ vol_spacing,
    const float* __restrict__ det_spacing,
    const float* __restrict__ angles,
    float* __restrict__ out)
{
    __shared__ f4v      s_csk[AH];                 // 4 KB: c, s, off-s0, bitcast(s0)
    __shared__ _Float16 s_win[CH * WIN * BB];      // 8 KB fp16 window

    const int tid = threadIdx.y * TSZ + threadIdx.x;
    const float inv_ds = 1.0f / det_spacing[0];
    const int abase = blockIdx.z * AH;

    const int x0 = blockIdx.x * TSZ;
    const int y0 = blockIdx.y * TSZ;
    const float vsx = vol_spacing[1], vsy = vol_spacing[0];
    const float off = -det_origin[0] * inv_ds;
    // Block-center coords; max tap deviation 7.5*(|c|+|s|) <= 10.7 bins, so
    // s0 = trunc(uc)-16 (clamped to [0, DD-WIN]) covers every pixel's taps
    // (u in (2.7, 725.3) for this geometry).
    const float xc = vol_origin[1] + ((float)x0 + 7.5f) * vsx;
    const float yc = vol_origin[0] + ((float)y0 + 7.5f) * vsy;

    for (int a = tid; a < AH; a += 256) {
        float th = angles[abase + a];
        float c = cosf(th) * inv_ds;
        float s = sinf(th) * inv_ds;
        float uc = fmaf(xc, c, fmaf(yc, s, off));
        int s0 = min(max((int)uc - (WIN / 2), 0), DD - WIN);
        f4v k;
        k.x = c; k.y = s; k.z = off - (float)s0; k.w = __int_as_float(s0);
        s_csk[a] = k;
    }
    __syncthreads();

    const int ix = x0 + threadIdx.x;
    const int iy = y0 + threadIdx.y;
    const float xw = vol_origin[1] + (float)ix * vsx;
    const float yw = vol_origin[0] + (float)iy * vsy;

    const __amdgpu_buffer_rsrc_t rsrc = __builtin_amdgcn_make_buffer_rsrc(
        (void*)sino, (short)0, BB * AA * DD * 4, 0x00020000);

    f4v acc = {0.f, 0.f, 0.f, 0.f};

    for (int a0 = 0; a0 < AH; a0 += CH) {
        // ---- stage CH angles x WIN bins x BB batches (4096 = 16/thread) ----
        #pragma unroll
        for (int k = 0; k < 16; ++k) {
            const int idx = k * 256 + tid;
            const int e   = idx & 31;          // bin (fastest: coalesced global)
            const int bb  = (idx >> 5) & 3;    // batch
            const int ja  = idx >> 7;          // local angle
            const int s0  = __float_as_int(s_csk[a0 + ja].w);
            const int gi  = bb * (AA * DD) + (abase + a0 + ja) * DD + s0 + e;
            s_win[(ja * WIN + e) * BB + bb] = (_Float16)buf_load1(rsrc, gi * 4);
        }
        __syncthreads();

        // ---- consume ----
        #pragma unroll 4
        for (int j = 0; j < CH; ++j) {
            const f4v   k  = s_csk[a0 + j];
            const float ul = fmaf(xw, k.x, fmaf(yw, k.y, k.z)); // u - s0 >= 0
            const int   li = (int)ul;                            // == floor
            const float fr = ul - (float)li;
            const h4v* w = (const h4v*)&s_win[(j * WIN + li) * BB];
            const f4v P = __builtin_convertvector(w[0], f4v);   // bin li,   4 batches
            const f4v Q = __builtin_convertvector(w[1], f4v);   // bin li+1, 4 batches
            const f4v fr4 = {fr, fr, fr, fr};
            acc = acc + P + fr4 * (Q - P);
        }
        __syncthreads();
    }

    const size_t HW = (size_t)HH * WW;
    const size_t o  = (size_t)iy * WW + ix;
    unsafeAtomicAdd(&out[o],          acc.x);
    unsafeAtomicAdd(&out[o + HW],     acc.y);
    unsafeAtomicAdd(&out[o + 2 * HW], acc.z);
    unsafeAtomicAdd(&out[o + 3 * HW], acc.w);
}

extern "C" void kernel_launch(void* const* d_in, const int* in_sizes, int n_in,
                              void* d_out, int out_size, void* d_ws, size_t ws_size,
                              hipStream_t stream) {
    const float* sino        = (const float*)d_in[0];
    // d_in[1] = volume_shape (int64) — compile-time constants HH/WW used.
    const float* vol_origin  = (const float*)d_in[2];
    const float* det_origin  = (const float*)d_in[3];
    const float* vol_spacing = (const float*)d_in[4];
    const float* det_spacing = (const float*)d_in[5];
    const float* angles      = (const float*)d_in[6];
    float* out = (float*)d_out;

    // Two grid-z halves accumulate atomically into a zeroed output.
    hipMemsetAsync(d_out, 0, (size_t)out_size * sizeof(float), stream);

    dim3 block(TSZ, TSZ, 1);
    dim3 grid(WW / TSZ, HH / TSZ, 2);
    bp_kernel<<<grid, block, 0, stream>>>(sino, vol_origin, det_origin,
                                          vol_spacing, det_spacing, angles, out);
}

// Round 13
// 150.448 us; speedup vs baseline: 1.0710x; 1.0710x over previous
//
#include <hip/hip_runtime.h>

#define BB 4
#define AA 512
#define AH 256   // angles per grid-z half
#define DD 729
#define HH 512
#define WW 512
#define TSZ 16   // pixel tile 16x16
#define CH  32   // angles staged per chunk
#define WIN 32   // window bins per angle

typedef float    f4v __attribute__((ext_vector_type(4)));
typedef _Float16 h4v __attribute__((ext_vector_type(4)));

__device__ inline float buf_load1(__amdgpu_buffer_rsrc_t r, int vo) {
    union { unsigned int u; float f; } c;
    c.u = __builtin_amdgcn_raw_buffer_load_b32(r, vo, 0, 0);
    return c.f;
}

// R12 post-mortem: fp16 window halved LDS bytes but __builtin_convertvector
// cost 8 scalar v_cvt_f32_f16/angle -> VALU busy-equiv 62->89us, net loss.
// R13: same fp16 window, but the lerp is written as fmaf(w,(float)h,acc) with
// _Float16 element extracts — clang's mad-mix combine folds the fpext into
// v_fma_mix_f32 (f16 src half via op_sel, f32 math): 8 fma_mix, ZERO cvts.
// Taps stay 2x ds_read_b64. Accuracy identical to R12 (absmax 0.5 << 1.97).
__global__ __launch_bounds__(256, 8) void bp_kernel(
    const float* __restrict__ sino,
    const float* __restrict__ vol_origin,
    const float* __restrict__ det_origin,
    const float* __restrict__ vol_spacing,
    const float* __restrict__ det_spacing,
    const float* __restrict__ angles,
    float* __restrict__ out)
{
    __shared__ f4v      s_csk[AH];                 // 4 KB: c, s, off-s0, bitcast(s0)
    __shared__ _Float16 s_win[CH * WIN * BB];      // 8 KB fp16 window

    const int tid = threadIdx.y * TSZ + threadIdx.x;
    const float inv_ds = 1.0f / det_spacing[0];
    const int abase = blockIdx.z * AH;

    const int x0 = blockIdx.x * TSZ;
    const int y0 = blockIdx.y * TSZ;
    const float vsx = vol_spacing[1], vsy = vol_spacing[0];
    const float off = -det_origin[0] * inv_ds;
    // Block-center coords; max tap deviation 7.5*(|c|+|s|) <= 10.7 bins, so
    // s0 = trunc(uc)-16 (clamped to [0, DD-WIN]) covers every pixel's taps
    // (u in (2.7, 725.3) for this geometry).
    const float xc = vol_origin[1] + ((float)x0 + 7.5f) * vsx;
    const float yc = vol_origin[0] + ((float)y0 + 7.5f) * vsy;

    for (int a = tid; a < AH; a += 256) {
        float th = angles[abase + a];
        float c = cosf(th) * inv_ds;
        float s = sinf(th) * inv_ds;
        float uc = fmaf(xc, c, fmaf(yc, s, off));
        int s0 = min(max((int)uc - (WIN / 2), 0), DD - WIN);
        f4v k;
        k.x = c; k.y = s; k.z = off - (float)s0; k.w = __int_as_float(s0);
        s_csk[a] = k;
    }
    __syncthreads();

    const int ix = x0 + threadIdx.x;
    const int iy = y0 + threadIdx.y;
    const float xw = vol_origin[1] + (float)ix * vsx;
    const float yw = vol_origin[0] + (float)iy * vsy;

    const __amdgpu_buffer_rsrc_t rsrc = __builtin_amdgcn_make_buffer_rsrc(
        (void*)sino, (short)0, BB * AA * DD * 4, 0x00020000);

    float a0c = 0.f, a1c = 0.f, a2c = 0.f, a3c = 0.f;

    for (int a0 = 0; a0 < AH; a0 += CH) {
        // ---- stage CH angles x WIN bins x BB batches (4096 = 16/thread) ----
        #pragma unroll
        for (int k = 0; k < 16; ++k) {
            const int idx = k * 256 + tid;
            const int e   = idx & 31;          // bin (fastest: coalesced global)
            const int bb  = (idx >> 5) & 3;    // batch
            const int ja  = idx >> 7;          // local angle
            const int s0  = __float_as_int(s_csk[a0 + ja].w);
            const int gi  = bb * (AA * DD) + (abase + a0 + ja) * DD + s0 + e;
            s_win[(ja * WIN + e) * BB + bb] = (_Float16)buf_load1(rsrc, gi * 4);
        }
        __syncthreads();

        // ---- consume ----
        #pragma unroll 4
        for (int j = 0; j < CH; ++j) {
            const f4v   k  = s_csk[a0 + j];
            const float ul = fmaf(xw, k.x, fmaf(yw, k.y, k.z)); // u - s0 >= 0
            const int   li = (int)ul;                            // == floor
            const float fr = ul - (float)li;
            const float omf = 1.0f - fr;
            const h4v* w = (const h4v*)&s_win[(j * WIN + li) * BB];
            const h4v P = w[0];     // bin li,   batches 0..3 (8B, ds_read_b64)
            const h4v Q = w[1];     // bin li+1, batches 0..3
            // (1-fr)*P + fr*Q per batch — each fmaf has one f16-extended
            // operand -> v_fma_mix_f32 (no cvt instructions).
            a0c = fmaf(fr, (float)Q.x, fmaf(omf, (float)P.x, a0c));
            a1c = fmaf(fr, (float)Q.y, fmaf(omf, (float)P.y, a1c));
            a2c = fmaf(fr, (float)Q.z, fmaf(omf, (float)P.z, a2c));
            a3c = fmaf(fr, (float)Q.w, fmaf(omf, (float)P.w, a3c));
        }
        __syncthreads();
    }

    const size_t HW = (size_t)HH * WW;
    const size_t o  = (size_t)iy * WW + ix;
    unsafeAtomicAdd(&out[o],          a0c);
    unsafeAtomicAdd(&out[o + HW],     a1c);
    unsafeAtomicAdd(&out[o + 2 * HW], a2c);
    unsafeAtomicAdd(&out[o + 3 * HW], a3c);
}

extern "C" void kernel_launch(void* const* d_in, const int* in_sizes, int n_in,
                              void* d_out, int out_size, void* d_ws, size_t ws_size,
                              hipStream_t stream) {
    const float* sino        = (const float*)d_in[0];
    // d_in[1] = volume_shape (int64) — compile-time constants HH/WW used.
    const float* vol_origin  = (const float*)d_in[2];
    const float* det_origin  = (const float*)d_in[3];
    const float* vol_spacing = (const float*)d_in[4];
    const float* det_spacing = (const float*)d_in[5];
    const float* angles      = (const float*)d_in[6];
    float* out = (float*)d_out;

    // Two grid-z halves accumulate atomically into a zeroed output.
    hipMemsetAsync(d_out, 0, (size_t)out_size * sizeof(float), stream);

    dim3 block(TSZ, TSZ, 1);
    dim3 grid(WW / TSZ, HH / TSZ, 2);
    bp_kernel<<<grid, block, 0, stream>>>(sino, vol_origin, det_origin,
                                          vol_spacing, det_spacing, angles, out);
}

// Round 14
// 142.774 us; speedup vs baseline: 1.1286x; 1.0537x over previous
//
#include <hip/hip_runtime.h>

#define BB 4
#define AA 512
#define ZS 4          // angle slices (grid.z)
#define AH (AA / ZS)  // 128 angles per slice
#define DD 729
#define HH 512
#define WW 512
#define CH 16         // angles staged per chunk
#define WIN 32        // window bins per angle

typedef float f4v __attribute__((ext_vector_type(4)));

// Async global->LDS, 4B per lane; LDS dest = wave-uniform base + lane*4.
__device__ inline void gload_lds(const float* g, float* l) {
    __builtin_amdgcn_global_load_lds(
        (const __attribute__((address_space(1))) unsigned int*)g,
        (__attribute__((address_space(3))) unsigned int*)l, 4, 0, 0);
}

// R13 post-mortem: VALU *instruction issue* is the wall (busy-equiv matches
// static count at 2cyc/instr/SIMD; LDS BW measured ~320 B/cyc/CU in R11 — not
// limiting). R14: fp32 window (no cvts), 2 px/thread in y (per-angle k/u setup
// amortized; fract_f32 for frac), 4-way z angle-split keeps 30 waves/CU, and
// global_load_lds staging (1 instr / 64 floats, no VGPR round-trip).
__global__ __launch_bounds__(128, 8) void bp_kernel(
    const float* __restrict__ sino,
    const float* __restrict__ vol_origin,
    const float* __restrict__ det_origin,
    const float* __restrict__ vol_spacing,
    const float* __restrict__ det_spacing,
    const float* __restrict__ angles,
    float* __restrict__ out)
{
    __shared__ f4v   s_csk[AH];            // 2 KB: c, s, off-s0, 8*vsy*s
    __shared__ int   s_s0[AH];             // 0.5 KB window starts
    __shared__ float s_win[CH * WIN * BB]; // 8 KB fp32: [j][e][bb]

    const int tid  = threadIdx.y * 16 + threadIdx.x;   // block 16x8
    const int lane = tid & 63;
    const int wv   = tid >> 6;                          // wave id (0,1)

    const float inv_ds = 1.0f / det_spacing[0];
    const int abase = blockIdx.z * AH;

    const int x0 = blockIdx.x * 16;
    const int y0 = blockIdx.y * 16;
    const float vsx = vol_spacing[1], vsy = vol_spacing[0];
    const float off = -det_origin[0] * inv_ds;
    // Tile 16x16 center; max tap deviation 7.5*(|c|+|s|) <= 10.7 bins ->
    // s0 = trunc(uc)-16 (clamped to [0, DD-WIN]) covers all taps (u in
    // (2.7, 725.3) for this geometry; coverage holds at the clamps).
    const float xc = vol_origin[1] + ((float)x0 + 7.5f) * vsx;
    const float yc = vol_origin[0] + ((float)y0 + 7.5f) * vsy;

    for (int a = tid; a < AH; a += 128) {
        float th = angles[abase + a];
        float c = cosf(th) * inv_ds;
        float s = sinf(th) * inv_ds;
        float uc = fmaf(xc, c, fmaf(yc, s, off));
        int s0 = min(max((int)uc - (WIN / 2), 0), DD - WIN);
        f4v k;
        k.x = c; k.y = s; k.z = off - (float)s0; k.w = 8.0f * vsy * s;
        s_csk[a] = k;
        s_s0[a]  = s0;
    }
    __syncthreads();

    // Pixels (ix, iyA) and (ix, iyA+8).
    const int ix  = x0 + threadIdx.x;
    const int iyA = y0 + threadIdx.y;
    const float xw = vol_origin[1] + (float)ix * vsx;
    const float yw = vol_origin[0] + (float)iyA * vsy;

    // Staging lane map (constant across iters): wave w covers elems
    // w*64..w*64+63 of one angle's 128-float window; e = idx>>2, bb = idx&3.
    const int sidx = wv * 64 + lane;
    const int se   = sidx >> 2;
    const int sbb  = lane & 3;
    const long sgoff = (long)sbb * (AA * DD) + se;   // element offset

    f4v accA = {0.f, 0.f, 0.f, 0.f};
    f4v accB = {0.f, 0.f, 0.f, 0.f};

    for (int a0 = 0; a0 < AH; a0 += CH) {
        // ---- stage: CH angles x 128 floats, 1 global_load_lds per wave-angle ----
        #pragma unroll
        for (int i = 0; i < CH; ++i) {
            const int  s0  = s_s0[a0 + i];
            const long row = (long)(abase + a0 + i) * DD + s0;
            gload_lds(sino + row + sgoff, &s_win[i * (WIN * BB) + wv * 64]);
        }
        __syncthreads();   // drains vmcnt for global_load_lds

        // ---- consume: 2 pixels/thread, shared per-angle setup ----
        #pragma unroll
        for (int j = 0; j < CH; ++j) {
            const f4v  k  = s_csk[a0 + j];
            const float u0 = fmaf(xw, k.x, fmaf(yw, k.y, k.z)); // u - s0 in [0,31)
            const float u1 = u0 + k.w;                           // pixel (ix, iyA+8)
            {
                const int   li = (int)u0;
                const float fr = __builtin_amdgcn_fractf(u0);
                const f4v* w = (const f4v*)&s_win[(j * WIN + li) * BB];
                const f4v P = w[0], Q = w[1];
                const f4v fr4 = {fr, fr, fr, fr};
                accA = accA + P + fr4 * (Q - P);
            }
            {
                const int   li = (int)u1;
                const float fr = __builtin_amdgcn_fractf(u1);
                const f4v* w = (const f4v*)&s_win[(j * WIN + li) * BB];
                const f4v P = w[0], Q = w[1];
                const f4v fr4 = {fr, fr, fr, fr};
                accB = accB + P + fr4 * (Q - P);
            }
        }
        __syncthreads();
    }

    const size_t HW = (size_t)HH * WW;
    const size_t oA = (size_t)iyA * WW + ix;
    const size_t oB = oA + (size_t)8 * WW;
    unsafeAtomicAdd(&out[oA],          accA.x);
    unsafeAtomicAdd(&out[oA + HW],     accA.y);
    unsafeAtomicAdd(&out[oA + 2 * HW], accA.z);
    unsafeAtomicAdd(&out[oA + 3 * HW], accA.w);
    unsafeAtomicAdd(&out[oB],          accB.x);
    unsafeAtomicAdd(&out[oB + HW],     accB.y);
    unsafeAtomicAdd(&out[oB + 2 * HW], accB.z);
    unsafeAtomicAdd(&out[oB + 3 * HW], accB.w);
}

extern "C" void kernel_launch(void* const* d_in, const int* in_sizes, int n_in,
                              void* d_out, int out_size, void* d_ws, size_t ws_size,
                              hipStream_t stream) {
    const float* sino        = (const float*)d_in[0];
    // d_in[1] = volume_shape (int64) — compile-time constants HH/WW used.
    const float* vol_origin  = (const float*)d_in[2];
    const float* det_origin  = (const float*)d_in[3];
    const float* vol_spacing = (const float*)d_in[4];
    const float* det_spacing = (const float*)d_in[5];
    const float* angles      = (const float*)d_in[6];
    float* out = (float*)d_out;

    // ZS grid-z slices accumulate atomically into a zeroed output.
    hipMemsetAsync(d_out, 0, (size_t)out_size * sizeof(float), stream);

    dim3 block(16, 8, 1);
    dim3 grid(WW / 16, HH / 16, ZS);
    bp_kernel<<<grid, block, 0, stream>>>(sino, vol_origin, det_origin,
                                          vol_spacing, det_spacing, angles, out);
}

// Round 15
// 136.245 us; speedup vs baseline: 1.1827x; 1.0479x over previous
//
#include <hip/hip_runtime.h>

#define BB 4
#define AA 512
#define ZS 4          // angle slices (grid.z)
#define AH (AA / ZS)  // 128 angles per slice
#define DD 729
#define HH 512
#define WW 512
#define CH 8          // angles per buffer (double-buffered)
#define WIN 32        // window bins per angle

typedef float f4v __attribute__((ext_vector_type(4)));

// Async global->LDS, 4B per lane; LDS dest = wave-uniform base + lane*4.
__device__ inline void gload_lds(const float* g, float* l) {
    __builtin_amdgcn_global_load_lds(
        (const __attribute__((address_space(1))) unsigned int*)g,
        (__attribute__((address_space(3))) unsigned int*)l, 4, 0, 0);
}

// R14 post-mortem: 88us = 55us VALU busy-equiv + ~33us stall; the serial
// stage->barrier->consume chunk loop issues loads only after the previous
// consume, so every barrier pays a full load-latency drain (m97 vmcnt(0)
// lesson). R15: double-buffered CH=8 windows — next chunk's global_load_lds
// issue BEFORE consuming the current one, giving them a whole consume phase
// to land; one barrier per chunk. Same 10.5 KB LDS -> 15 blocks/CU. Lerp
// refactored to acc + fr*Q + (1-fr)*P = 4x v_pk_fma_f32 (no pk_sub).
__global__ __launch_bounds__(128, 8) void bp_kernel(
    const float* __restrict__ sino,
    const float* __restrict__ vol_origin,
    const float* __restrict__ det_origin,
    const float* __restrict__ vol_spacing,
    const float* __restrict__ det_spacing,
    const float* __restrict__ angles,
    float* __restrict__ out)
{
    __shared__ f4v   s_csk[AH];                // 2 KB: c, s, off-s0, 8*vsy*s
    __shared__ int   s_s0[AH];                 // 0.5 KB window starts
    __shared__ float s_win[2][CH * WIN * BB];  // 2 x 4 KB fp32: [j][e][bb]

    const int tid  = threadIdx.y * 16 + threadIdx.x;   // block 16x8
    const int lane = tid & 63;
    const int wv   = tid >> 6;                          // wave id (0,1)

    const float inv_ds = 1.0f / det_spacing[0];
    const int abase = blockIdx.z * AH;

    const int x0 = blockIdx.x * 16;
    const int y0 = blockIdx.y * 16;
    const float vsx = vol_spacing[1], vsy = vol_spacing[0];
    const float off = -det_origin[0] * inv_ds;
    // Tile 16x16 center; max tap deviation 7.5*(|c|+|s|) <= 10.7 bins ->
    // s0 = trunc(uc)-16 (clamped to [0, DD-WIN]) covers all taps (u in
    // (2.7, 725.3) for this geometry; coverage holds at the clamps).
    const float xc = vol_origin[1] + ((float)x0 + 7.5f) * vsx;
    const float yc = vol_origin[0] + ((float)y0 + 7.5f) * vsy;

    for (int a = tid; a < AH; a += 128) {
        float th = angles[abase + a];
        float c = cosf(th) * inv_ds;
        float s = sinf(th) * inv_ds;
        float uc = fmaf(xc, c, fmaf(yc, s, off));
        int s0 = min(max((int)uc - (WIN / 2), 0), DD - WIN);
        f4v k;
        k.x = c; k.y = s; k.z = off - (float)s0; k.w = 8.0f * vsy * s;
        s_csk[a] = k;
        s_s0[a]  = s0;
    }
    __syncthreads();

    // Pixels (ix, iyA) and (ix, iyA+8).
    const int ix  = x0 + threadIdx.x;
    const int iyA = y0 + threadIdx.y;
    const float xw = vol_origin[1] + (float)ix * vsx;
    const float yw = vol_origin[0] + (float)iyA * vsy;

    // Staging lane map: wave w covers floats w*64..w*64+63 of an angle's
    // 128-float window ([e][bb], bb = lane&3 fastest).
    const int sidx = wv * 64 + lane;
    const long sgoff = (long)(lane & 3) * (AA * DD) + (sidx >> 2);

    f4v accA = {0.f, 0.f, 0.f, 0.f};
    f4v accB = {0.f, 0.f, 0.f, 0.f};

    // ---- double-buffered chunk pipeline ----
    #define STAGE(A0, P)                                                   \
        do {                                                               \
            _Pragma("unroll")                                              \
            for (int i = 0; i < CH; ++i) {                                 \
                const int  s0  = s_s0[(A0) + i];                           \
                const long row = (long)(abase + (A0) + i) * DD + s0;       \
                gload_lds(sino + row + sgoff,                              \
                          &s_win[P][i * (WIN * BB) + wv * 64]);            \
            }                                                              \
        } while (0)

    int p = 0;
    STAGE(0, 0);
    for (int a0 = 0; a0 < AH; a0 += CH) {
        __syncthreads();                       // buffer p's loads drained
        if (a0 + CH < AH) STAGE(a0 + CH, p ^ 1);   // prefetch into other buf
        #pragma unroll
        for (int j = 0; j < CH; ++j) {
            const f4v  k  = s_csk[a0 + j];
            const float u0 = fmaf(xw, k.x, fmaf(yw, k.y, k.z)); // u-s0 in [0,31)
            const float u1 = u0 + k.w;                           // (ix, iyA+8)
            {
                const int   li = (int)u0;
                const float fr = __builtin_amdgcn_fractf(u0);
                const float om = 1.0f - fr;
                const f4v* w = (const f4v*)&s_win[p][(j * WIN + li) * BB];
                const f4v P = w[0], Q = w[1];
                const f4v fr4 = {fr, fr, fr, fr};
                const f4v om4 = {om, om, om, om};
                accA = accA + fr4 * Q + om4 * P;   // 4x v_pk_fma_f32
            }
            {
                const int   li = (int)u1;
                const float fr = __builtin_amdgcn_fractf(u1);
                const float om = 1.0f - fr;
                const f4v* w = (const f4v*)&s_win[p][(j * WIN + li) * BB];
                const f4v P = w[0], Q = w[1];
                const f4v fr4 = {fr, fr, fr, fr};
                const f4v om4 = {om, om, om, om};
                accB = accB + fr4 * Q + om4 * P;
            }
        }
        p ^= 1;
    }
    #undef STAGE

    const size_t HW = (size_t)HH * WW;
    const size_t oA = (size_t)iyA * WW + ix;
    const size_t oB = oA + (size_t)8 * WW;
    unsafeAtomicAdd(&out[oA],          accA.x);
    unsafeAtomicAdd(&out[oA + HW],     accA.y);
    unsafeAtomicAdd(&out[oA + 2 * HW], accA.z);
    unsafeAtomicAdd(&out[oA + 3 * HW], accA.w);
    unsafeAtomicAdd(&out[oB],          accB.x);
    unsafeAtomicAdd(&out[oB + HW],     accB.y);
    unsafeAtomicAdd(&out[oB + 2 * HW], accB.z);
    unsafeAtomicAdd(&out[oB + 3 * HW], accB.w);
}

extern "C" void kernel_launch(void* const* d_in, const int* in_sizes, int n_in,
                              void* d_out, int out_size, void* d_ws, size_t ws_size,
                              hipStream_t stream) {
    const float* sino        = (const float*)d_in[0];
    // d_in[1] = volume_shape (int64) — compile-time constants HH/WW used.
    const float* vol_origin  = (const float*)d_in[2];
    const float* det_origin  = (const float*)d_in[3];
    const float* vol_spacing = (const float*)d_in[4];
    const float* det_spacing = (const float*)d_in[5];
    const float* angles      = (const float*)d_in[6];
    float* out = (float*)d_out;

    // ZS grid-z slices accumulate atomically into a zeroed output.
    hipMemsetAsync(d_out, 0, (size_t)out_size * sizeof(float), stream);

    dim3 block(16, 8, 1);
    dim3 grid(WW / 16, HH / 16, ZS);
    bp_kernel<<<grid, block, 0, stream>>>(sino, vol_origin, det_origin,
                                          vol_spacing, det_spacing, angles, out);
}